// Round 2
// baseline (2228.218 us; speedup 1.0000x reference)
//
#include <hip/hip_runtime.h>
#include <hip/hip_bf16.h>
#include <math.h>

// Problem constants (fixed by reference setup_inputs)
#define N_NODES 262144      // S*T
#define SSTMT   16384
#define TT      16
#define DD      128
#define HH      3
#define HD      384         // H*D
#define EPSV    1e-5f

// ===========================================================================
// 64-row kernels (FULL path + layer-0 stats pass)
// ===========================================================================

// Fused GAT layer 0: per block 64 statement-aligned rows. Computes layer-0
// output (post relu), optionally writes r0 (fp32), always writes BN partials.
__global__ __launch_bounds__(256, 1)
void gat0_fused(const float* __restrict__ x, const float* __restrict__ W0,
                const float* __restrict__ as0, const float* __restrict__ ad0,
                const float* __restrict__ b0,
                float* __restrict__ r0, int writeR0, float* __restrict__ pA0)
{
    __shared__ float xsT[128][68];     // k-major x tile: xsT[k][row]
    __shared__ float wc[128][128];     // W0 head slice: wc[k][c]
    __shared__ float h0s[64][132];     // computed h tile (fp32)
    __shared__ float als[64], ald[64], aS[64], aN[64];
    __shared__ float asl[128], adl[128];
    __shared__ float bnps[8][128], bnpq[8][128];

    const int tid = threadIdx.x;
    const int bid = blockIdx.x;
    const long rb = (long)bid * 64;

    {
        int row = tid & 63, k4 = tid >> 6;               // k4 in 0..3
        const float* xp = x + (rb + row) * (long)DD + k4 * 32;
        #pragma unroll
        for (int j = 0; j < 8; ++j) {
            float4 v = *reinterpret_cast<const float4*>(xp + j * 4);
            int kb = k4 * 32 + j * 4;
            xsT[kb + 0][row] = v.x;
            xsT[kb + 1][row] = v.y;
            xsT[kb + 2][row] = v.z;
            xsT[kb + 3][row] = v.w;
        }
    }

    const int rg = tid >> 5;       // 0..7  (8 rows each)
    const int c4 = (tid & 31) * 4; // 4 cols each

    for (int h = 0; h < HH; ++h) {
        #pragma unroll
        for (int i = 0; i < 16; ++i) {
            int gi = i * 256 + tid;
            int k  = gi >> 5;
            int cc = (gi & 31) * 4;
            float4 v = *reinterpret_cast<const float4*>(&W0[(size_t)k * HD + h * 128 + cc]);
            *reinterpret_cast<float4*>(&wc[k][cc]) = v;
        }
        if (tid < 128) { asl[tid] = as0[h * 128 + tid]; adl[tid] = ad0[h * 128 + tid]; }
        __syncthreads();

        float acc[8][4];
        #pragma unroll
        for (int i = 0; i < 8; ++i)
            #pragma unroll
            for (int j = 0; j < 4; ++j) acc[i][j] = 0.f;

        #pragma unroll 8
        for (int k = 0; k < 128; ++k) {
            float4 b4 = *reinterpret_cast<const float4*>(&wc[k][c4]);
            float4 a0 = *reinterpret_cast<const float4*>(&xsT[k][rg * 8]);
            float4 a1 = *reinterpret_cast<const float4*>(&xsT[k][rg * 8 + 4]);
            float av[8] = {a0.x, a0.y, a0.z, a0.w, a1.x, a1.y, a1.z, a1.w};
            float bv[4] = {b4.x, b4.y, b4.z, b4.w};
            #pragma unroll
            for (int i = 0; i < 8; ++i)
                #pragma unroll
                for (int j = 0; j < 4; ++j)
                    acc[i][j] += av[i] * bv[j];
        }
        #pragma unroll
        for (int i = 0; i < 8; ++i) {
            int r = rg * 8 + i;
            float4 v; v.x = acc[i][0]; v.y = acc[i][1]; v.z = acc[i][2]; v.w = acc[i][3];
            *reinterpret_cast<float4*>(&h0s[r][c4]) = v;
        }
        __syncthreads();

        if (tid < 128) {
            int r = tid & 63;
            const bool isrc = (tid < 64);
            const float* av = isrc ? asl : adl;
            float s = 0.f;
            for (int cc = 0; cc < 128; ++cc) {
                int c = (cc + r) & 127;
                s += h0s[r][c] * av[c];
            }
            if (isrc) als[r] = s; else ald[r] = s;
        }
        __syncthreads();

        if (tid < 64) {
            int r = tid;
            float es = als[r] + ald[r];
            es = es > 0.f ? es : 0.2f * es;
            float aSv, aNv;
            if ((r & 15) != 15) {
                float en = als[r + 1] + ald[r];
                en = en > 0.f ? en : 0.2f * en;
                float m = fmaxf(es, en);
                float xs_ = expf(es - m), xn_ = expf(en - m);
                float den = xs_ + xn_;
                aSv = xs_ / den; aNv = xn_ / den;
            } else { aSv = 1.f; aNv = 0.f; }
            aS[r] = aSv; aN[r] = aNv;
        }
        __syncthreads();

        {
            float ps[4] = {0, 0, 0, 0}, pq[4] = {0, 0, 0, 0};
            const float* bp = b0 + h * 128;
            float bb[4] = {bp[c4], bp[c4 + 1], bp[c4 + 2], bp[c4 + 3]};
            #pragma unroll
            for (int i = 0; i < 8; ++i) {
                int r = rg * 8 + i;
                float a_s = aS[r], a_n = aN[r];
                float4 hv = *reinterpret_cast<const float4*>(&h0s[r][c4]);
                float v0, v1, v2, v3;
                if ((r & 15) != 15) {
                    float4 hx = *reinterpret_cast<const float4*>(&h0s[r + 1][c4]);
                    v0 = a_s * hv.x + a_n * hx.x;
                    v1 = a_s * hv.y + a_n * hx.y;
                    v2 = a_s * hv.z + a_n * hx.z;
                    v3 = a_s * hv.w + a_n * hx.w;
                } else {
                    v0 = hv.x; v1 = hv.y; v2 = hv.z; v3 = hv.w;
                }
                float o0 = fmaxf(v0 + bb[0], 0.f);
                float o1 = fmaxf(v1 + bb[1], 0.f);
                float o2 = fmaxf(v2 + bb[2], 0.f);
                float o3 = fmaxf(v3 + bb[3], 0.f);
                if (writeR0) {
                    float4 ov; ov.x = o0; ov.y = o1; ov.z = o2; ov.w = o3;
                    *reinterpret_cast<float4*>(&r0[((size_t)(rb + r)) * HD + h * 128 + c4]) = ov;
                }
                ps[0] += o0; pq[0] += o0 * o0;
                ps[1] += o1; pq[1] += o1 * o1;
                ps[2] += o2; pq[2] += o2 * o2;
                ps[3] += o3; pq[3] += o3 * o3;
            }
            #pragma unroll
            for (int j = 0; j < 4; ++j) { bnps[rg][c4 + j] = ps[j]; bnpq[rg][c4 + j] = pq[j]; }
        }
        __syncthreads();
        if (tid < 128) {
            int c = tid;
            float s = 0.f, q = 0.f;
            #pragma unroll
            for (int g2 = 0; g2 < 8; ++g2) { s += bnps[g2][c]; q += bnpq[g2][c]; }
            size_t idx = ((size_t)bid * HD + h * 128 + c) * 2;
            pA0[idx] = s; pA0[idx + 1] = q;
        }
        __syncthreads();
    }
}

// FULL-path GAT layer 1 (reads stored r0; BN0 scale folded into W1, shift into c1v)
__global__ __launch_bounds__(256, 1)
void gat1_fused(const float* __restrict__ r0, const float* __restrict__ W1,
                const float* __restrict__ sc0, const float* __restrict__ c1v,
                const float* __restrict__ as1, const float* __restrict__ ad1,
                const float* __restrict__ b1,
                float* __restrict__ r1, float* __restrict__ pA1)
{
    __shared__ float xsT[128][68];
    __shared__ float wc[128][128];
    __shared__ float hhs[64][132];
    __shared__ float als[64], ald[64], aS[64], aN[64];
    __shared__ float asl[128], adl[128];
    __shared__ float bnps[8][128], bnpq[8][128];

    const int tid = threadIdx.x;
    const int bid = blockIdx.x;
    const long rb = (long)bid * 64;

    const int rg = tid >> 5;
    const int c4 = (tid & 31) * 4;

    float acc[8][4];
    #pragma unroll
    for (int i = 0; i < 8; ++i)
        #pragma unroll
        for (int j = 0; j < 4; ++j) acc[i][j] = 0.f;

    for (int kc = 0; kc < 3; ++kc) {
        {
            int row = tid & 63, k4 = tid >> 6;
            const float* xp = r0 + (rb + row) * (size_t)HD + kc * 128 + k4 * 32;
            #pragma unroll
            for (int j = 0; j < 8; ++j) {
                float4 v = *reinterpret_cast<const float4*>(xp + j * 4);
                int kb = k4 * 32 + j * 4;
                xsT[kb + 0][row] = v.x;
                xsT[kb + 1][row] = v.y;
                xsT[kb + 2][row] = v.z;
                xsT[kb + 3][row] = v.w;
            }
        }
        #pragma unroll
        for (int i = 0; i < 16; ++i) {
            int gi = i * 256 + tid;
            int kk = gi >> 5;
            int cc = (gi & 31) * 4;
            int k  = kc * 128 + kk;
            float s = sc0[k];
            float4 v = *reinterpret_cast<const float4*>(&W1[(size_t)k * 128 + cc]);
            v.x *= s; v.y *= s; v.z *= s; v.w *= s;
            *reinterpret_cast<float4*>(&wc[kk][cc]) = v;
        }
        if (kc == 0 && tid < 128) { asl[tid] = as1[tid]; adl[tid] = ad1[tid]; }
        __syncthreads();

        #pragma unroll 8
        for (int k = 0; k < 128; ++k) {
            float4 b4 = *reinterpret_cast<const float4*>(&wc[k][c4]);
            float4 a0 = *reinterpret_cast<const float4*>(&xsT[k][rg * 8]);
            float4 a1 = *reinterpret_cast<const float4*>(&xsT[k][rg * 8 + 4]);
            float av[8] = {a0.x, a0.y, a0.z, a0.w, a1.x, a1.y, a1.z, a1.w};
            float bv[4] = {b4.x, b4.y, b4.z, b4.w};
            #pragma unroll
            for (int i = 0; i < 8; ++i)
                #pragma unroll
                for (int j = 0; j < 4; ++j)
                    acc[i][j] += av[i] * bv[j];
        }
        __syncthreads();
    }

    {
        float4 c1 = *reinterpret_cast<const float4*>(&c1v[c4]);
        #pragma unroll
        for (int i = 0; i < 8; ++i) {
            int r = rg * 8 + i;
            float4 v;
            v.x = acc[i][0] + c1.x; v.y = acc[i][1] + c1.y;
            v.z = acc[i][2] + c1.z; v.w = acc[i][3] + c1.w;
            *reinterpret_cast<float4*>(&hhs[r][c4]) = v;
        }
    }
    __syncthreads();

    if (tid < 128) {
        int r = tid & 63;
        const bool isrc = (tid < 64);
        const float* av = isrc ? asl : adl;
        float s = 0.f;
        for (int cc = 0; cc < 128; ++cc) {
            int c = (cc + r) & 127;
            s += hhs[r][c] * av[c];
        }
        if (isrc) als[r] = s; else ald[r] = s;
    }
    __syncthreads();

    if (tid < 64) {
        int r = tid;
        float es = als[r] + ald[r];
        es = es > 0.f ? es : 0.2f * es;
        float aSv, aNv;
        if ((r & 15) != 15) {
            float en = als[r + 1] + ald[r];
            en = en > 0.f ? en : 0.2f * en;
            float m = fmaxf(es, en);
            float xs_ = expf(es - m), xn_ = expf(en - m);
            float den = xs_ + xn_;
            aSv = xs_ / den; aNv = xn_ / den;
        } else { aSv = 1.f; aNv = 0.f; }
        aS[r] = aSv; aN[r] = aNv;
    }
    __syncthreads();

    {
        float ps[4] = {0, 0, 0, 0}, pq[4] = {0, 0, 0, 0};
        float bb[4] = {b1[c4], b1[c4 + 1], b1[c4 + 2], b1[c4 + 3]};
        #pragma unroll
        for (int i = 0; i < 8; ++i) {
            int r = rg * 8 + i;
            float a_s = aS[r], a_n = aN[r];
            float4 hv = *reinterpret_cast<const float4*>(&hhs[r][c4]);
            float v0, v1, v2, v3;
            if ((r & 15) != 15) {
                float4 hx = *reinterpret_cast<const float4*>(&hhs[r + 1][c4]);
                v0 = a_s * hv.x + a_n * hx.x;
                v1 = a_s * hv.y + a_n * hx.y;
                v2 = a_s * hv.z + a_n * hx.z;
                v3 = a_s * hv.w + a_n * hx.w;
            } else {
                v0 = hv.x; v1 = hv.y; v2 = hv.z; v3 = hv.w;
            }
            float o0 = fmaxf(v0 + bb[0], 0.f);
            float o1 = fmaxf(v1 + bb[1], 0.f);
            float o2 = fmaxf(v2 + bb[2], 0.f);
            float o3 = fmaxf(v3 + bb[3], 0.f);
            float4 ov; ov.x = o0; ov.y = o1; ov.z = o2; ov.w = o3;
            *reinterpret_cast<float4*>(&r1[((size_t)(rb + r)) * DD + c4]) = ov;
            ps[0] += o0; pq[0] += o0 * o0;
            ps[1] += o1; pq[1] += o1 * o1;
            ps[2] += o2; pq[2] += o2 * o2;
            ps[3] += o3; pq[3] += o3 * o3;
        }
        #pragma unroll
        for (int j = 0; j < 4; ++j) { bnps[rg][c4 + j] = ps[j]; bnpq[rg][c4 + j] = pq[j]; }
    }
    __syncthreads();
    if (tid < 128) {
        int c = tid;
        float s = 0.f, q = 0.f;
        #pragma unroll
        for (int g2 = 0; g2 < 8; ++g2) { s += bnps[g2][c]; q += bnpq[g2][c]; }
        size_t idx = ((size_t)bid * DD + c) * 2;
        pA1[idx] = s; pA1[idx + 1] = q;
    }
}

// ===========================================================================
// 32-row recompute machinery (RECOMP / TINY paths)
// ===========================================================================

// Computes the post-layer1 (aggregated + b1 + relu) 32x128 tile for rows
// [rb, rb+32) into hs, recomputing layer 0 with BN0 (sc0/sh0) applied.
__device__ __forceinline__ void compute_r1_tile(
    long rb, const float* __restrict__ x, const float* __restrict__ W0,
    const float* __restrict__ as0, const float* __restrict__ ad0,
    const float* __restrict__ b0, const float* __restrict__ sc0,
    const float* __restrict__ sh0, const float* __restrict__ W1,
    const float* __restrict__ as1, const float* __restrict__ ad1,
    const float* __restrict__ b1,
    float (*xs)[36], float (*wc)[132], float (*hs)[132], float (*r0T)[128][36],
    float* als, float* ald, float* aSa, float* aNa, float* avs, float* avd)
{
    const int tid = threadIdx.x;
    const int rg = tid >> 5;        // 0..7 -> rows rg*4 .. rg*4+3
    const int c4 = (tid & 31) * 4;  // cols c4 .. c4+3

    // stage x tile k-major
    {
        int row = tid & 31, kq = tid >> 5;   // kq 0..7
        const float* xp = x + (size_t)(rb + row) * DD + kq * 16;
        #pragma unroll
        for (int j = 0; j < 4; ++j) {
            float4 v = *reinterpret_cast<const float4*>(xp + j * 4);
            int kb = kq * 16 + j * 4;
            xs[kb + 0][row] = v.x;
            xs[kb + 1][row] = v.y;
            xs[kb + 2][row] = v.z;
            xs[kb + 3][row] = v.w;
        }
    }

    // -------- layer 0, per head --------
    for (int h = 0; h < HH; ++h) {
        float acc[4][4];
        #pragma unroll
        for (int i = 0; i < 4; ++i)
            #pragma unroll
            for (int j = 0; j < 4; ++j) acc[i][j] = 0.f;

        for (int kc = 0; kc < 2; ++kc) {
            __syncthreads();   // wc (and xs on first pass) safe to (re)use after this
            #pragma unroll
            for (int i = 0; i < 8; ++i) {
                int gi = i * 256 + tid;          // 0..2047
                int kk = gi >> 5;                // 0..63
                int cg = (gi & 31) * 4;          // 0..124
                float4 v = *reinterpret_cast<const float4*>(
                    &W0[(size_t)(kc * 64 + kk) * HD + h * 128 + cg]);
                *reinterpret_cast<float4*>(&wc[kk][cg]) = v;
            }
            if (kc == 0 && tid < 128) { avs[tid] = as0[h * 128 + tid]; avd[tid] = ad0[h * 128 + tid]; }
            __syncthreads();
            #pragma unroll 4
            for (int k = 0; k < 64; ++k) {
                float4 a = *reinterpret_cast<const float4*>(&xs[kc * 64 + k][rg * 4]);
                float4 b = *reinterpret_cast<const float4*>(&wc[k][c4]);
                acc[0][0] += a.x * b.x; acc[0][1] += a.x * b.y; acc[0][2] += a.x * b.z; acc[0][3] += a.x * b.w;
                acc[1][0] += a.y * b.x; acc[1][1] += a.y * b.y; acc[1][2] += a.y * b.z; acc[1][3] += a.y * b.w;
                acc[2][0] += a.z * b.x; acc[2][1] += a.z * b.y; acc[2][2] += a.z * b.z; acc[2][3] += a.z * b.w;
                acc[3][0] += a.w * b.x; acc[3][1] += a.w * b.y; acc[3][2] += a.w * b.z; acc[3][3] += a.w * b.w;
            }
        }
        __syncthreads();   // hs free (previous consumers done)
        #pragma unroll
        for (int i = 0; i < 4; ++i) {
            float4 v; v.x = acc[i][0]; v.y = acc[i][1]; v.z = acc[i][2]; v.w = acc[i][3];
            *reinterpret_cast<float4*>(&hs[rg * 4 + i][c4]) = v;
        }
        __syncthreads();

        // attention logits
        if (tid < 64) {
            int r = tid & 31;
            const float* av = (tid < 32) ? avs : avd;
            float s = 0.f;
            for (int cc = 0; cc < 128; ++cc) {
                int c = (cc + r * 4) & 127;
                s += hs[r][c] * av[c];
            }
            if (tid < 32) als[r] = s; else ald[r] = s;
        }
        __syncthreads();
        if (tid < 32) {
            int r = tid;
            float es = als[r] + ald[r];
            es = es > 0.f ? es : 0.2f * es;
            float aSv, aNv;
            if ((r & 15) != 15) {
                float en = als[r + 1] + ald[r];
                en = en > 0.f ? en : 0.2f * en;
                float m = fmaxf(es, en);
                float xs_ = expf(es - m), xn_ = expf(en - m);
                float den = xs_ + xn_;
                aSv = xs_ / den; aNv = xn_ / den;
            } else { aSv = 1.f; aNv = 0.f; }
            aSa[r] = aSv; aNa[r] = aNv;
        }
        __syncthreads();

        // aggregate + b0 + relu + BN0 -> r0T[h] (k-major)
        #pragma unroll
        for (int i = 0; i < 4; ++i) {
            int r = rg * 4 + i;
            float a_s = aSa[r], a_n = aNa[r];
            bool hasn = ((r & 15) != 15);
            #pragma unroll
            for (int j = 0; j < 4; ++j) {
                int c = c4 + j;
                float v = hs[r][c];
                if (hasn) v = a_s * v + a_n * hs[r + 1][c];
                float o = fmaxf(v + b0[h * 128 + c], 0.f);
                r0T[h][c][r] = o * sc0[h * 128 + c] + sh0[h * 128 + c];
            }
        }
        // next-head wc restage has a leading __syncthreads()
    }

    // -------- layer 1: GEMM K=384 over r0T --------
    float acc2[4][4];
    #pragma unroll
    for (int i = 0; i < 4; ++i)
        #pragma unroll
        for (int j = 0; j < 4; ++j) acc2[i][j] = 0.f;

    for (int kc = 0; kc < 6; ++kc) {
        __syncthreads();
        #pragma unroll
        for (int i = 0; i < 8; ++i) {
            int gi = i * 256 + tid;
            int kk = gi >> 5;
            int cg = (gi & 31) * 4;
            float4 v = *reinterpret_cast<const float4*>(&W1[(size_t)(kc * 64 + kk) * DD + cg]);
            *reinterpret_cast<float4*>(&wc[kk][cg]) = v;
        }
        if (kc == 0 && tid < 128) { avs[tid] = as1[tid]; avd[tid] = ad1[tid]; }
        __syncthreads();
        const float (*a0T)[36] = r0T[kc >> 1];
        const int kbase = (kc & 1) * 64;
        #pragma unroll 4
        for (int k = 0; k < 64; ++k) {
            float4 a = *reinterpret_cast<const float4*>(&a0T[kbase + k][rg * 4]);
            float4 b = *reinterpret_cast<const float4*>(&wc[k][c4]);
            acc2[0][0] += a.x * b.x; acc2[0][1] += a.x * b.y; acc2[0][2] += a.x * b.z; acc2[0][3] += a.x * b.w;
            acc2[1][0] += a.y * b.x; acc2[1][1] += a.y * b.y; acc2[1][2] += a.y * b.z; acc2[1][3] += a.y * b.w;
            acc2[2][0] += a.z * b.x; acc2[2][1] += a.z * b.y; acc2[2][2] += a.z * b.z; acc2[2][3] += a.z * b.w;
            acc2[3][0] += a.w * b.x; acc2[3][1] += a.w * b.y; acc2[3][2] += a.w * b.z; acc2[3][3] += a.w * b.w;
        }
    }
    __syncthreads();
    #pragma unroll
    for (int i = 0; i < 4; ++i) {
        float4 v; v.x = acc2[i][0]; v.y = acc2[i][1]; v.z = acc2[i][2]; v.w = acc2[i][3];
        *reinterpret_cast<float4*>(&hs[rg * 4 + i][c4]) = v;   // hh (pre-bias)
    }
    __syncthreads();

    if (tid < 64) {
        int r = tid & 31;
        const float* av = (tid < 32) ? avs : avd;
        float s = 0.f;
        for (int cc = 0; cc < 128; ++cc) {
            int c = (cc + r * 4) & 127;
            s += hs[r][c] * av[c];
        }
        if (tid < 32) als[r] = s; else ald[r] = s;
    }
    __syncthreads();
    if (tid < 32) {
        int r = tid;
        float es = als[r] + ald[r];
        es = es > 0.f ? es : 0.2f * es;
        float aSv, aNv;
        if ((r & 15) != 15) {
            float en = als[r + 1] + ald[r];
            en = en > 0.f ? en : 0.2f * en;
            float m = fmaxf(es, en);
            float xs_ = expf(es - m), xn_ = expf(en - m);
            float den = xs_ + xn_;
            aSv = xs_ / den; aNv = xn_ / den;
        } else { aSv = 1.f; aNv = 0.f; }
        aSa[r] = aSv; aNa[r] = aNv;
    }
    __syncthreads();

    // aggregate + b1 + relu -> regs, then write back into hs in-place
    float rr[4][4];
    #pragma unroll
    for (int i = 0; i < 4; ++i) {
        int r = rg * 4 + i;
        float a_s = aSa[r], a_n = aNa[r];
        bool hasn = ((r & 15) != 15);
        #pragma unroll
        for (int j = 0; j < 4; ++j) {
            int c = c4 + j;
            float v = hs[r][c];
            if (hasn) v = a_s * v + a_n * hs[r + 1][c];
            rr[i][j] = fmaxf(v + b1[c], 0.f);
        }
    }
    __syncthreads();
    #pragma unroll
    for (int i = 0; i < 4; ++i) {
        float4 v; v.x = rr[i][0]; v.y = rr[i][1]; v.z = rr[i][2]; v.w = rr[i][3];
        *reinterpret_cast<float4*>(&hs[rg * 4 + i][c4]) = v;
    }
    __syncthreads();
}

// RECOMP/TINY pass 3: recompute layer0+layer1 for 32 rows; write r1 (optional)
// and BN1 partials.
__global__ __launch_bounds__(256, 1)
void gat1_recomp(const float* __restrict__ x, const float* __restrict__ W0,
                 const float* __restrict__ as0, const float* __restrict__ ad0,
                 const float* __restrict__ b0, const float* __restrict__ sc0,
                 const float* __restrict__ sh0, const float* __restrict__ W1,
                 const float* __restrict__ as1, const float* __restrict__ ad1,
                 const float* __restrict__ b1,
                 float* __restrict__ r1, int writeR1, float* __restrict__ pA1)
{
    __shared__ float xs[128][36];
    __shared__ float wc[64][132];
    __shared__ float hs[32][132];
    __shared__ float r0T[3][128][36];
    __shared__ float als[32], ald[32], aSa[32], aNa[32];
    __shared__ float avs[128], avd[128];
    __shared__ float bnp[8][128], bnq[8][128];

    const int tid = threadIdx.x;
    const int bid = blockIdx.x;
    const long rb = (long)bid * 32;

    compute_r1_tile(rb, x, W0, as0, ad0, b0, sc0, sh0, W1, as1, ad1, b1,
                    xs, wc, hs, r0T, als, ald, aSa, aNa, avs, avd);

    const int rg = tid >> 5;
    const int c4 = (tid & 31) * 4;
    float ps[4] = {0, 0, 0, 0}, pq[4] = {0, 0, 0, 0};
    #pragma unroll
    for (int i = 0; i < 4; ++i) {
        int r = rg * 4 + i;
        float4 v = *reinterpret_cast<const float4*>(&hs[r][c4]);
        if (writeR1)
            *reinterpret_cast<float4*>(&r1[(size_t)(rb + r) * DD + c4]) = v;
        ps[0] += v.x; pq[0] += v.x * v.x;
        ps[1] += v.y; pq[1] += v.y * v.y;
        ps[2] += v.z; pq[2] += v.z * v.z;
        ps[3] += v.w; pq[3] += v.w * v.w;
    }
    #pragma unroll
    for (int j = 0; j < 4; ++j) { bnp[rg][c4 + j] = ps[j]; bnq[rg][c4 + j] = pq[j]; }
    __syncthreads();
    if (tid < 128) {
        int c = tid;
        float s = 0.f, q = 0.f;
        #pragma unroll
        for (int g2 = 0; g2 < 8; ++g2) { s += bnp[g2][c]; q += bnq[g2][c]; }
        size_t idx = ((size_t)bid * DD + c) * 2;
        pA1[idx] = s; pA1[idx + 1] = q;
    }
}

// TINY pass 5: recompute layers, apply BN1, pool 2 statements, MLP.
__global__ __launch_bounds__(256, 1)
void pool_recomp(const float* __restrict__ x, const float* __restrict__ W0,
                 const float* __restrict__ as0, const float* __restrict__ ad0,
                 const float* __restrict__ b0, const float* __restrict__ sc0,
                 const float* __restrict__ sh0, const float* __restrict__ W1,
                 const float* __restrict__ as1, const float* __restrict__ ad1,
                 const float* __restrict__ b1,
                 const float* __restrict__ sc1, const float* __restrict__ sh1,
                 const float* __restrict__ pn,
                 const float* __restrict__ mW1, const float* __restrict__ mb1,
                 const float* __restrict__ mW2, const float* __restrict__ mb2,
                 float* __restrict__ out)
{
    __shared__ float xs[128][36];
    __shared__ float wc[64][132];
    __shared__ float hs[32][132];
    __shared__ float r0T[3][128][36];
    __shared__ float als[32], ald[32], aSa[32], aNa[32];
    __shared__ float avs[128], avd[128];
    __shared__ float sv[32], tv[32];
    __shared__ float pooled[2][128];
    __shared__ float y1[2][32];

    const int tid = threadIdx.x;
    const int bid = blockIdx.x;
    const long rb = (long)bid * 32;

    compute_r1_tile(rb, x, W0, as0, ad0, b0, sc0, sh0, W1, as1, ad1, b1,
                    xs, wc, hs, r0T, als, ald, aSa, aNa, avs, avd);

    // apply BN1 in place (each thread updates its own 16 cells)
    {
        const int rg = tid >> 5;
        const int c4 = (tid & 31) * 4;
        #pragma unroll
        for (int i = 0; i < 4; ++i) {
            int r = rg * 4 + i;
            #pragma unroll
            for (int j = 0; j < 4; ++j) {
                int c = c4 + j;
                hs[r][c] = hs[r][c] * sc1[c] + sh1[c];
            }
        }
    }
    __syncthreads();

    // scores: 8 threads per row (32 rows x 8 = 256)
    {
        int r = tid >> 3, q = tid & 7;
        float s = 0.f;
        #pragma unroll
        for (int cc = 0; cc < 16; ++cc) {
            int c = q + cc * 8;
            s += hs[r][c] * pn[c];
        }
        s += __shfl_down(s, 4, 8);
        s += __shfl_down(s, 2, 8);
        s += __shfl_down(s, 1, 8);
        if (q == 0) sv[r] = s;
    }
    __syncthreads();

    // top-8 per statement (2 statements/block), stable ties
    if (tid < 32) {
        int st = tid >> 4;
        float si = sv[tid];
        int rank = 0;
        #pragma unroll
        for (int u = 0; u < 16; ++u) {
            int ug = st * 16 + u;
            float su = sv[ug];
            rank += (su > si || (su == si && ug < tid)) ? 1 : 0;
        }
        tv[tid] = (rank < 8) ? tanhf(si) : 0.f;
    }
    __syncthreads();

    // pooled per statement
    {
        int st = tid >> 7, c = tid & 127;
        float a = 0.f;
        #pragma unroll
        for (int u = 0; u < 16; ++u) {
            int r = st * 16 + u;
            a += fmaxf(hs[r][c] * tv[r], 0.f);
        }
        pooled[st][c] = a * 0.125f;
    }
    __syncthreads();

    // y1 = relu(pooled @ mW1 + mb1): per statement, 4 threads per output
    {
        int st = tid >> 7, local = tid & 127;
        int j = local >> 2, q = local & 3;
        float a = 0.f;
        #pragma unroll
        for (int cc = 0; cc < 32; ++cc) {
            int c = q + cc * 4;
            a += pooled[st][c] * mW1[(size_t)c * 32 + j];
        }
        a += __shfl_down(a, 2, 4);
        a += __shfl_down(a, 1, 4);
        if (q == 0) y1[st][j] = fmaxf(a + mb1[j], 0.f);
    }
    __syncthreads();

    // out = y1 @ mW2 + mb2
    {
        int st = tid >> 7, c = tid & 127;
        float o = mb2[c];
        #pragma unroll
        for (int j = 0; j < 32; ++j) o += y1[st][j] * mW2[j * 128 + c];
        out[((size_t)bid * 2 + st) * 128 + c] = o;
    }
}

// ===========================================================================
// Small helper kernels
// ===========================================================================

__global__ __launch_bounds__(256)
void bn_reduce(const float* __restrict__ pA, int nblk, int ncol, float invN,
               const float* __restrict__ g, const float* __restrict__ be,
               float* __restrict__ sc, float* __restrict__ sh)
{
    __shared__ float rs[256], rq[256];
    int col = blockIdx.x, tid = threadIdx.x;
    float s = 0.f, q = 0.f;
    for (int i = tid; i < nblk; i += 256) {
        size_t idx = ((size_t)i * ncol + col) * 2;
        s += pA[idx]; q += pA[idx + 1];
    }
    rs[tid] = s; rq[tid] = q;
    __syncthreads();
    for (int o = 128; o > 0; o >>= 1) {
        if (tid < o) { rs[tid] += rs[tid + o]; rq[tid] += rq[tid + o]; }
        __syncthreads();
    }
    if (tid == 0) {
        float mu  = rs[0] * invN;
        float var = fmaxf(rq[0] * invN - mu * mu, 0.f);
        float inv = 1.0f / sqrtf(var + EPSV);
        float scv = g[col] * inv;
        sc[col] = scv;
        sh[col] = be[col] - mu * scv;
    }
}

__global__ __launch_bounds__(128)
void compute_c1(const float* __restrict__ sh0, const float* __restrict__ W1,
                float* __restrict__ c1v)
{
    int j = threadIdx.x;
    float a = 0.f;
    for (int k = 0; k < HD; ++k) a += sh0[k] * W1[(size_t)k * 128 + j];
    c1v[j] = a;
}

__global__ __launch_bounds__(128)
void compute_pn(const float* __restrict__ p, float* __restrict__ pn)
{
    __shared__ float rs[128];
    int t = threadIdx.x;
    float v = p[t];
    rs[t] = v * v;
    __syncthreads();
    for (int o = 64; o > 0; o >>= 1) {
        if (t < o) rs[t] += rs[t + o];
        __syncthreads();
    }
    float nrm = sqrtf(rs[0]) + 1e-16f;
    pn[t] = v / nrm;
}

// FULL/RECOMP pass 5: pool + MLP reading stored r1
__global__ __launch_bounds__(128)
void pool_mlp(const float* __restrict__ r1, const float* __restrict__ sc1,
              const float* __restrict__ sh1, const float* __restrict__ pn,
              const float* __restrict__ mW1, const float* __restrict__ mb1,
              const float* __restrict__ mW2, const float* __restrict__ mb2,
              float* __restrict__ out)
{
    __shared__ float hf[16][136];
    __shared__ float sv[16];
    __shared__ float tv[16];
    __shared__ float pooled[128];
    __shared__ float y1[32];
    int tid = threadIdx.x;
    int sid = blockIdx.x;
    float scv = sc1[tid], shv = sh1[tid];
    const float* base = r1 + (size_t)sid * TT * DD;
    #pragma unroll
    for (int i = 0; i < 16; ++i)
        hf[i][tid] = base[i * DD + tid] * scv + shv;
    __syncthreads();

    {
        int r = tid >> 3, q = tid & 7;
        float s = 0.f;
        #pragma unroll
        for (int cc = 0; cc < 16; ++cc) {
            int c = q + cc * 8;
            s += hf[r][c] * pn[c];
        }
        s += __shfl_down(s, 4, 8);
        s += __shfl_down(s, 2, 8);
        s += __shfl_down(s, 1, 8);
        if (q == 0) sv[r] = s;
    }
    __syncthreads();

    if (tid < 16) {
        float si = sv[tid];
        int rank = 0;
        #pragma unroll
        for (int u = 0; u < 16; ++u) {
            float su = sv[u];
            rank += (su > si || (su == si && u < tid)) ? 1 : 0;
        }
        tv[tid] = (rank < 8) ? tanhf(si) : 0.f;
    }
    __syncthreads();

    {
        float a = 0.f;
        #pragma unroll
        for (int rr = 0; rr < 16; ++rr)
            a += fmaxf(hf[rr][tid] * tv[rr], 0.f);
        pooled[tid] = a * 0.125f;
    }
    __syncthreads();

    {
        int j = tid >> 2, q = tid & 3;
        float a = 0.f;
        #pragma unroll
        for (int cc = 0; cc < 32; ++cc) {
            int c = q + cc * 4;
            a += pooled[c] * mW1[(size_t)c * 32 + j];
        }
        a += __shfl_down(a, 2, 4);
        a += __shfl_down(a, 1, 4);
        if (q == 0) y1[j] = fmaxf(a + mb1[j], 0.f);
    }
    __syncthreads();

    {
        float o = mb2[tid];
        #pragma unroll
        for (int j = 0; j < 32; ++j) o += y1[j] * mW2[j * 128 + tid];
        out[(size_t)sid * 128 + tid] = o;
    }
}

// ===========================================================================
extern "C" void kernel_launch(void* const* d_in, const int* in_sizes, int n_in,
                              void* d_out, int out_size, void* d_ws, size_t ws_size,
                              hipStream_t stream)
{
    (void)in_sizes; (void)n_in; (void)out_size;
    const float* x   = (const float*)d_in[0];
    const float* W0  = (const float*)d_in[1];
    const float* as0 = (const float*)d_in[2];
    const float* ad0 = (const float*)d_in[3];
    const float* b0  = (const float*)d_in[4];
    const float* g0  = (const float*)d_in[5];
    const float* be0 = (const float*)d_in[6];
    const float* W1  = (const float*)d_in[7];
    const float* as1 = (const float*)d_in[8];
    const float* ad1 = (const float*)d_in[9];
    const float* b1  = (const float*)d_in[10];
    const float* g1  = (const float*)d_in[11];
    const float* be1 = (const float*)d_in[12];
    const float* p   = (const float*)d_in[13];
    const float* mW1 = (const float*)d_in[14];
    const float* mb1 = (const float*)d_in[15];
    const float* mW2 = (const float*)d_in[16];
    const float* mb2 = (const float*)d_in[17];
    float* out = (float*)d_out;

    const size_t R0B  = (size_t)N_NODES * HD * 4;     // 402,653,184
    const size_t R1B  = (size_t)N_NODES * DD * 4;     // 134,217,728
    const size_t PA0B = 4096ull * HD * 2 * 4;         //  12,582,912
    const size_t PA1B = 8192ull * DD * 2 * 4;         //   8,388,608
    const size_t VECB = 3072 * 4;                     //      12,288

    const size_t need_full = R0B + R1B + PA0B + PA1B + VECB;
    const size_t need_rec  = R1B + PA0B + PA1B + VECB;
    const size_t need_tiny = PA0B + PA1B + VECB;
    (void)need_tiny;

    // mode: 2 = FULL (store r0+r1), 1 = RECOMP (store r1 only), 0 = TINY
    const int mode = (ws_size >= need_full + 4096) ? 2
                   : (ws_size >= need_rec  + 4096) ? 1 : 0;

    char* ws = (char*)d_ws;
    float* r0  = nullptr;
    float* r1  = nullptr;
    float* pA0;
    float* pA1;
    float* vec;
    if (mode == 2) {
        r0  = (float*)ws;
        r1  = (float*)(ws + R0B);
        pA0 = (float*)(ws + R0B + R1B);
        pA1 = (float*)(ws + R0B + R1B + PA0B);
        vec = (float*)(ws + R0B + R1B + PA0B + PA1B);
    } else if (mode == 1) {
        r1  = (float*)ws;
        pA0 = (float*)(ws + R1B);
        pA1 = (float*)(ws + R1B + PA0B);
        vec = (float*)(ws + R1B + PA0B + PA1B);
    } else {
        pA0 = (float*)ws;
        pA1 = (float*)(ws + PA0B);
        vec = (float*)(ws + PA0B + PA1B);
    }
    float* sc0 = vec;
    float* sh0 = vec + 512;
    float* sc1 = vec + 1024;
    float* sh1 = vec + 1536;
    float* pn  = vec + 2048;
    float* c1v = vec + 2560;

    const float invN = 1.0f / (float)N_NODES;

    // pass 1: layer0 (+ r0 store in FULL) + BN0 partials
    gat0_fused<<<N_NODES / 64, 256, 0, stream>>>(x, W0, as0, ad0, b0,
                                                 mode == 2 ? r0 : pA0, mode == 2 ? 1 : 0, pA0);
    bn_reduce<<<HD, 256, 0, stream>>>(pA0, N_NODES / 64, HD, invN, g0, be0, sc0, sh0);
    compute_pn<<<1, 128, 0, stream>>>(p, pn);

    if (mode == 2) {
        compute_c1<<<1, 128, 0, stream>>>(sh0, W1, c1v);
        gat1_fused<<<N_NODES / 64, 256, 0, stream>>>(r0, W1, sc0, c1v, as1, ad1, b1, r1, pA1);
        bn_reduce<<<DD, 256, 0, stream>>>(pA1, N_NODES / 64, DD, invN, g1, be1, sc1, sh1);
        pool_mlp<<<SSTMT, 128, 0, stream>>>(r1, sc1, sh1, pn, mW1, mb1, mW2, mb2, out);
    } else {
        gat1_recomp<<<N_NODES / 32, 256, 0, stream>>>(x, W0, as0, ad0, b0, sc0, sh0,
                                                      W1, as1, ad1, b1,
                                                      mode == 1 ? r1 : pA1, mode == 1 ? 1 : 0, pA1);
        bn_reduce<<<DD, 256, 0, stream>>>(pA1, N_NODES / 32, DD, invN, g1, be1, sc1, sh1);
        if (mode == 1) {
            pool_mlp<<<SSTMT, 128, 0, stream>>>(r1, sc1, sh1, pn, mW1, mb1, mW2, mb2, out);
        } else {
            pool_recomp<<<N_NODES / 32, 256, 0, stream>>>(x, W0, as0, ad0, b0, sc0, sh0,
                                                          W1, as1, ad1, b1, sc1, sh1, pn,
                                                          mW1, mb1, mW2, mb2, out);
        }
    }
}

// Round 3
// 1834.856 us; speedup vs baseline: 1.2144x; 1.2144x over previous
//
#include <hip/hip_runtime.h>
#include <math.h>

// Problem constants (fixed by reference setup_inputs)
#define N_NODES 262144      // S*T
#define SSTMT   16384
#define TT      16
#define DD      128
#define HH      3
#define HD      384         // H*D
#define EPSV    1e-5f

// ---------------------------------------------------------------------------
// Helpers
// ---------------------------------------------------------------------------

// stage a [32][128] fp32 tile row-major from global; 256 threads, 4 float4 each
__device__ __forceinline__ void stage32x128(float (*dst)[128], const float* __restrict__ src,
                                            size_t srcStride)
{
    const int tid = threadIdx.x;
    #pragma unroll
    for (int j = 0; j < 4; ++j) {
        int gi = j * 256 + tid;          // 0..1023
        int row = gi >> 5;               // 0..31
        int col = (gi & 31) * 4;
        float4 v = *reinterpret_cast<const float4*>(&src[(size_t)row * srcStride + col]);
        *reinterpret_cast<float4*>(&dst[row][col]) = v;
    }
}

// acc[i][j] += A[rg*4+i][kbase+k] * B[k][c4+j], k in [0,32)
// A-reads: same address across each half-wave (broadcast, conflict-free).
// B-reads: 512B contiguous per half-wave (clean b128).
__device__ __forceinline__ void gemm32(const float (*A)[128], int kbase, const float (*B)[128],
                                       int rg, int c4, float acc[4][4])
{
    #pragma unroll
    for (int k4 = 0; k4 < 8; ++k4) {
        float4 a0 = *reinterpret_cast<const float4*>(&A[rg * 4 + 0][kbase + k4 * 4]);
        float4 a1 = *reinterpret_cast<const float4*>(&A[rg * 4 + 1][kbase + k4 * 4]);
        float4 a2 = *reinterpret_cast<const float4*>(&A[rg * 4 + 2][kbase + k4 * 4]);
        float4 a3 = *reinterpret_cast<const float4*>(&A[rg * 4 + 3][kbase + k4 * 4]);
        float4 b0 = *reinterpret_cast<const float4*>(&B[k4 * 4 + 0][c4]);
        float4 b1 = *reinterpret_cast<const float4*>(&B[k4 * 4 + 1][c4]);
        float4 b2 = *reinterpret_cast<const float4*>(&B[k4 * 4 + 2][c4]);
        float4 b3 = *reinterpret_cast<const float4*>(&B[k4 * 4 + 3][c4]);
        float a[4][4] = {{a0.x, a0.y, a0.z, a0.w},
                         {a1.x, a1.y, a1.z, a1.w},
                         {a2.x, a2.y, a2.z, a2.w},
                         {a3.x, a3.y, a3.z, a3.w}};
        float b[4][4] = {{b0.x, b0.y, b0.z, b0.w},
                         {b1.x, b1.y, b1.z, b1.w},
                         {b2.x, b2.y, b2.z, b2.w},
                         {b3.x, b3.y, b3.z, b3.w}};
        #pragma unroll
        for (int i = 0; i < 4; ++i)
            #pragma unroll
            for (int m = 0; m < 4; ++m)
                #pragma unroll
                for (int j = 0; j < 4; ++j)
                    acc[i][j] += a[i][m] * b[m][j];
    }
}

// attention logits + 2-edge segment softmax for a 32-row statement-aligned tile
__device__ __forceinline__ void attn32(const float (*hsv)[128],
                                       const float* __restrict__ avs, const float* __restrict__ avd,
                                       float* als, float* ald, float* aSw, float* aNw)
{
    const int tid = threadIdx.x;
    if (tid < 64) {
        int r = tid & 31;
        const float* av = (tid < 32) ? avs : avd;
        float s = 0.f;
        #pragma unroll 8
        for (int cc = 0; cc < 128; ++cc) {
            int c = (cc + r) & 127;       // rotate: conflict-free across 32 lanes
            s += hsv[r][c] * av[c];
        }
        if (tid < 32) als[r] = s; else ald[r] = s;
    }
    __syncthreads();
    if (tid < 32) {
        int r = tid;
        float es = als[r] + ald[r];
        es = es > 0.f ? es : 0.2f * es;
        float aSv = 1.f, aNv = 0.f;
        if ((r & 15) != 15) {
            float en = als[r + 1] + ald[r];
            en = en > 0.f ? en : 0.2f * en;
            float m = fmaxf(es, en);
            float xse = expf(es - m), xne = expf(en - m);
            float den = xse + xne;
            aSv = xse / den; aNv = xne / den;
        }
        aSw[r] = aSv; aNw[r] = aNv;
    }
    __syncthreads();
}

// ---------------------------------------------------------------------------
// Pass 1: layer-0 forward for BN0 statistics only (no r0 storage).
// Grid 4096 x 256 thr; each block: 2 subtiles of 32 statement-aligned rows.
// LDS ~49.5KB -> 3 blocks/CU.
// ---------------------------------------------------------------------------
__global__ __launch_bounds__(256, 3)
void gat0_stats(const float* __restrict__ x, const float* __restrict__ W0,
                const float* __restrict__ as0, const float* __restrict__ ad0,
                const float* __restrict__ b0, float* __restrict__ pA0)
{
    __shared__ float xs[32][128];
    __shared__ float wc[32][128];
    __shared__ float hs[32][128];
    __shared__ float avs[128], avd[128];
    __shared__ float als[32], ald[32], aSw[32], aNw[32];

    const int tid = threadIdx.x;
    const int bid = blockIdx.x;
    const int rg = tid >> 5;          // 0..7 -> rows rg*4..rg*4+3
    const int c4 = (tid & 31) * 4;    // cols c4..c4+3

    float psum[3][4], qsum[3][4];
    #pragma unroll
    for (int h = 0; h < HH; ++h)
        #pragma unroll
        for (int j = 0; j < 4; ++j) { psum[h][j] = 0.f; qsum[h][j] = 0.f; }

    for (int t = 0; t < 2; ++t) {
        const size_t rb = (size_t)bid * 64 + (size_t)t * 32;
        __syncthreads();                       // previous readers of xs done
        stage32x128(xs, x + rb * DD, DD);

        for (int h = 0; h < HH; ++h) {
            float acc[4][4];
            #pragma unroll
            for (int i = 0; i < 4; ++i)
                #pragma unroll
                for (int j = 0; j < 4; ++j) acc[i][j] = 0.f;

            for (int kc = 0; kc < 4; ++kc) {
                __syncthreads();               // wc readers done
                stage32x128(wc, W0 + (size_t)(kc * 32) * HD + h * DD, HD);
                if (kc == 0 && tid < 128) { avs[tid] = as0[h * DD + tid]; avd[tid] = ad0[h * DD + tid]; }
                __syncthreads();
                gemm32(xs, kc * 32, wc, rg, c4, acc);
            }

            __syncthreads();                   // hs readers (prev head aggregate) done
            #pragma unroll
            for (int i = 0; i < 4; ++i) {
                float4 v; v.x = acc[i][0]; v.y = acc[i][1]; v.z = acc[i][2]; v.w = acc[i][3];
                *reinterpret_cast<float4*>(&hs[rg * 4 + i][c4]) = v;
            }
            __syncthreads();
            attn32(hs, avs, avd, als, ald, aSw, aNw);

            // aggregate + bias + relu -> stats (no store needed)
            float4 bb = *reinterpret_cast<const float4*>(&b0[h * DD + c4]);
            #pragma unroll
            for (int i = 0; i < 4; ++i) {
                int r = rg * 4 + i;
                float4 hv = *reinterpret_cast<const float4*>(&hs[r][c4]);
                float4 hx = hv;
                if ((r & 15) != 15) hx = *reinterpret_cast<const float4*>(&hs[r + 1][c4]);
                float a_s = aSw[r], a_n = aNw[r];
                float o0 = fmaxf(a_s * hv.x + a_n * hx.x + bb.x, 0.f);
                float o1 = fmaxf(a_s * hv.y + a_n * hx.y + bb.y, 0.f);
                float o2 = fmaxf(a_s * hv.z + a_n * hx.z + bb.z, 0.f);
                float o3 = fmaxf(a_s * hv.w + a_n * hx.w + bb.w, 0.f);
                psum[h][0] += o0; qsum[h][0] += o0 * o0;
                psum[h][1] += o1; qsum[h][1] += o1 * o1;
                psum[h][2] += o2; qsum[h][2] += o2 * o2;
                psum[h][3] += o3; qsum[h][3] += o3 * o3;
            }
        }
    }

    // flush per-head BN0 partials through wc space (free now)
    float* bna = &wc[0][0];                    // 4096 floats available
    for (int h = 0; h < HH; ++h) {
        __syncthreads();
        #pragma unroll
        for (int j = 0; j < 4; ++j) {
            float s = psum[h][j] + __shfl_down(psum[h][j], 32);
            float q = qsum[h][j] + __shfl_down(qsum[h][j], 32);
            if ((tid & 63) < 32) {
                int w = tid >> 6;
                bna[w * 128 + c4 + j] = s;
                bna[512 + w * 128 + c4 + j] = q;
            }
        }
        __syncthreads();
        if (tid < 128) {
            float s = bna[tid] + bna[128 + tid] + bna[256 + tid] + bna[384 + tid];
            float q = bna[512 + tid] + bna[640 + tid] + bna[768 + tid] + bna[896 + tid];
            size_t idx = ((size_t)bid * HD + h * DD + tid) * 2;
            pA0[idx] = s; pA0[idx + 1] = q;
        }
    }
}

// ---------------------------------------------------------------------------
// Pass 3: recompute layer-0 (with BN0 applied), per-head-interleaved layer-1
// GEMM accumulation, layer-1 attention, write r1 + BN1 partials.
// Grid 4096 x 256 thr; 2 subtiles of 32 rows; LDS ~49.5KB -> 3 blocks/CU.
// ---------------------------------------------------------------------------
__global__ __launch_bounds__(256, 3)
void gat1_recomp(const float* __restrict__ x, const float* __restrict__ W0,
                 const float* __restrict__ as0, const float* __restrict__ ad0,
                 const float* __restrict__ b0, const float* __restrict__ sc0,
                 const float* __restrict__ sh0, const float* __restrict__ W1,
                 const float* __restrict__ as1, const float* __restrict__ ad1,
                 const float* __restrict__ b1,
                 float* __restrict__ r1, float* __restrict__ pA1)
{
    __shared__ float xs[32][128];
    __shared__ float wc[32][128];
    __shared__ float hs[32][128];
    __shared__ float avs[128], avd[128];
    __shared__ float als[32], ald[32], aSw[32], aNw[32];

    const int tid = threadIdx.x;
    const int bid = blockIdx.x;
    const int rg = tid >> 5;
    const int c4 = (tid & 31) * 4;

    float ps1[4] = {0, 0, 0, 0}, pq1[4] = {0, 0, 0, 0};

    for (int t = 0; t < 2; ++t) {
        const size_t rb = (size_t)bid * 64 + (size_t)t * 32;
        __syncthreads();
        stage32x128(xs, x + rb * DD, DD);

        float acc2[4][4];                      // layer-1 accumulator (K=384)
        #pragma unroll
        for (int i = 0; i < 4; ++i)
            #pragma unroll
            for (int j = 0; j < 4; ++j) acc2[i][j] = 0.f;

        for (int h = 0; h < HH; ++h) {
            // ---- layer-0 GEMM for head h ----
            float acc[4][4];
            #pragma unroll
            for (int i = 0; i < 4; ++i)
                #pragma unroll
                for (int j = 0; j < 4; ++j) acc[i][j] = 0.f;

            for (int kc = 0; kc < 4; ++kc) {
                __syncthreads();
                stage32x128(wc, W0 + (size_t)(kc * 32) * HD + h * DD, HD);
                if (kc == 0 && tid < 128) { avs[tid] = as0[h * DD + tid]; avd[tid] = ad0[h * DD + tid]; }
                __syncthreads();
                gemm32(xs, kc * 32, wc, rg, c4, acc);
            }

            __syncthreads();                   // hs readers (prev head layer-1 gemm) done
            #pragma unroll
            for (int i = 0; i < 4; ++i) {
                float4 v; v.x = acc[i][0]; v.y = acc[i][1]; v.z = acc[i][2]; v.w = acc[i][3];
                *reinterpret_cast<float4*>(&hs[rg * 4 + i][c4]) = v;
            }
            __syncthreads();
            attn32(hs, avs, avd, als, ald, aSw, aNw);

            // ---- aggregate + b0 + relu + BN0 -> regs ----
            float4 bb  = *reinterpret_cast<const float4*>(&b0[h * DD + c4]);
            float4 scv = *reinterpret_cast<const float4*>(&sc0[h * DD + c4]);
            float4 shv = *reinterpret_cast<const float4*>(&sh0[h * DD + c4]);
            float rr[4][4];
            #pragma unroll
            for (int i = 0; i < 4; ++i) {
                int r = rg * 4 + i;
                float4 hv = *reinterpret_cast<const float4*>(&hs[r][c4]);
                float4 hx = hv;
                if ((r & 15) != 15) hx = *reinterpret_cast<const float4*>(&hs[r + 1][c4]);
                float a_s = aSw[r], a_n = aNw[r];
                rr[i][0] = fmaxf(a_s * hv.x + a_n * hx.x + bb.x, 0.f) * scv.x + shv.x;
                rr[i][1] = fmaxf(a_s * hv.y + a_n * hx.y + bb.y, 0.f) * scv.y + shv.y;
                rr[i][2] = fmaxf(a_s * hv.z + a_n * hx.z + bb.z, 0.f) * scv.z + shv.z;
                rr[i][3] = fmaxf(a_s * hv.w + a_n * hx.w + bb.w, 0.f) * scv.w + shv.w;
            }
            __syncthreads();                   // all reads of hs done
            #pragma unroll
            for (int i = 0; i < 4; ++i) {
                float4 v; v.x = rr[i][0]; v.y = rr[i][1]; v.z = rr[i][2]; v.w = rr[i][3];
                *reinterpret_cast<float4*>(&hs[rg * 4 + i][c4]) = v;
            }
            __syncthreads();

            // ---- layer-1 partial GEMM: k chunk h*128..h*128+127 ----
            for (int kc = 0; kc < 4; ++kc) {
                __syncthreads();
                stage32x128(wc, W1 + (size_t)(h * 128 + kc * 32) * DD, DD);
                __syncthreads();
                gemm32(hs, kc * 32, wc, rg, c4, acc2);
            }
        }

        // ---- layer-1 attention ----
        __syncthreads();                       // layer-1 gemm reads of hs done
        #pragma unroll
        for (int i = 0; i < 4; ++i) {
            float4 v; v.x = acc2[i][0]; v.y = acc2[i][1]; v.z = acc2[i][2]; v.w = acc2[i][3];
            *reinterpret_cast<float4*>(&hs[rg * 4 + i][c4]) = v;
        }
        if (tid < 128) { avs[tid] = as1[tid]; avd[tid] = ad1[tid]; }
        __syncthreads();
        attn32(hs, avs, avd, als, ald, aSw, aNw);

        // aggregate + b1 + relu -> r1 + BN1 partial
        float4 bb1 = *reinterpret_cast<const float4*>(&b1[c4]);
        #pragma unroll
        for (int i = 0; i < 4; ++i) {
            int r = rg * 4 + i;
            float4 hv = *reinterpret_cast<const float4*>(&hs[r][c4]);
            float4 hx = hv;
            if ((r & 15) != 15) hx = *reinterpret_cast<const float4*>(&hs[r + 1][c4]);
            float a_s = aSw[r], a_n = aNw[r];
            float o0 = fmaxf(a_s * hv.x + a_n * hx.x + bb1.x, 0.f);
            float o1 = fmaxf(a_s * hv.y + a_n * hx.y + bb1.y, 0.f);
            float o2 = fmaxf(a_s * hv.z + a_n * hx.z + bb1.z, 0.f);
            float o3 = fmaxf(a_s * hv.w + a_n * hx.w + bb1.w, 0.f);
            float4 ov; ov.x = o0; ov.y = o1; ov.z = o2; ov.w = o3;
            *reinterpret_cast<float4*>(&r1[(rb + r) * DD + c4]) = ov;
            ps1[0] += o0; pq1[0] += o0 * o0;
            ps1[1] += o1; pq1[1] += o1 * o1;
            ps1[2] += o2; pq1[2] += o2 * o2;
            ps1[3] += o3; pq1[3] += o3 * o3;
        }
    }

    // flush BN1 partials via wc space
    float* bna = &wc[0][0];
    __syncthreads();
    #pragma unroll
    for (int j = 0; j < 4; ++j) {
        float s = ps1[j] + __shfl_down(ps1[j], 32);
        float q = pq1[j] + __shfl_down(pq1[j], 32);
        if ((tid & 63) < 32) {
            int w = tid >> 6;
            bna[w * 128 + c4 + j] = s;
            bna[512 + w * 128 + c4 + j] = q;
        }
    }
    __syncthreads();
    if (tid < 128) {
        float s = bna[tid] + bna[128 + tid] + bna[256 + tid] + bna[384 + tid];
        float q = bna[512 + tid] + bna[640 + tid] + bna[768 + tid] + bna[896 + tid];
        size_t idx = ((size_t)bid * DD + tid) * 2;
        pA1[idx] = s; pA1[idx + 1] = q;
    }
}

// ---------------------------------------------------------------------------
// BN stat reduction: per column, sum partials -> scale/shift
// ---------------------------------------------------------------------------
__global__ __launch_bounds__(256)
void bn_reduce(const float* __restrict__ pA, int nblk, int ncol, float invN,
               const float* __restrict__ g, const float* __restrict__ be,
               float* __restrict__ sc, float* __restrict__ sh)
{
    __shared__ float rs[256], rq[256];
    int col = blockIdx.x, tid = threadIdx.x;
    float s = 0.f, q = 0.f;
    for (int i = tid; i < nblk; i += 256) {
        size_t idx = ((size_t)i * ncol + col) * 2;
        s += pA[idx]; q += pA[idx + 1];
    }
    rs[tid] = s; rq[tid] = q;
    __syncthreads();
    for (int o = 128; o > 0; o >>= 1) {
        if (tid < o) { rs[tid] += rs[tid + o]; rq[tid] += rq[tid + o]; }
        __syncthreads();
    }
    if (tid == 0) {
        float mu  = rs[0] * invN;
        float var = fmaxf(rq[0] * invN - mu * mu, 0.f);
        float inv = 1.0f / sqrtf(var + EPSV);
        float scv = g[col] * inv;
        sc[col] = scv;
        sh[col] = be[col] - mu * scv;
    }
}

__global__ __launch_bounds__(128)
void compute_pn(const float* __restrict__ p, float* __restrict__ pn)
{
    __shared__ float rs[128];
    int t = threadIdx.x;
    float v = p[t];
    rs[t] = v * v;
    __syncthreads();
    for (int o = 64; o > 0; o >>= 1) {
        if (t < o) rs[t] += rs[t + o];
        __syncthreads();
    }
    float nrm = sqrtf(rs[0]) + 1e-16f;
    pn[t] = v / nrm;
}

// ---------------------------------------------------------------------------
// Pass 5: per-statement BN1 affine + score + top-8 + tanh-weighted relu mean
// + MLP 128->32->128
// ---------------------------------------------------------------------------
__global__ __launch_bounds__(128)
void pool_mlp(const float* __restrict__ r1, const float* __restrict__ sc1,
              const float* __restrict__ sh1, const float* __restrict__ pn,
              const float* __restrict__ mW1, const float* __restrict__ mb1,
              const float* __restrict__ mW2, const float* __restrict__ mb2,
              float* __restrict__ out)
{
    __shared__ float hf[16][136];
    __shared__ float sv[16];
    __shared__ float tv[16];
    __shared__ float pooled[128];
    __shared__ float y1[32];
    int tid = threadIdx.x;
    int sid = blockIdx.x;
    float scv = sc1[tid], shv = sh1[tid];
    const float* base = r1 + (size_t)sid * TT * DD;
    #pragma unroll
    for (int i = 0; i < 16; ++i)
        hf[i][tid] = base[i * DD + tid] * scv + shv;
    __syncthreads();

    {
        int r = tid >> 3, q = tid & 7;
        float s = 0.f;
        #pragma unroll
        for (int cc = 0; cc < 16; ++cc) {
            int c = q + cc * 8;
            s += hf[r][c] * pn[c];
        }
        s += __shfl_down(s, 4, 8);
        s += __shfl_down(s, 2, 8);
        s += __shfl_down(s, 1, 8);
        if (q == 0) sv[r] = s;
    }
    __syncthreads();

    if (tid < 16) {
        float si = sv[tid];
        int rank = 0;
        #pragma unroll
        for (int u = 0; u < 16; ++u) {
            float su = sv[u];
            rank += (su > si || (su == si && u < tid)) ? 1 : 0;
        }
        tv[tid] = (rank < 8) ? tanhf(si) : 0.f;
    }
    __syncthreads();

    {
        float a = 0.f;
        #pragma unroll
        for (int rr = 0; rr < 16; ++rr)
            a += fmaxf(hf[rr][tid] * tv[rr], 0.f);
        pooled[tid] = a * 0.125f;
    }
    __syncthreads();

    {
        int j = tid >> 2, q = tid & 3;
        float a = 0.f;
        #pragma unroll
        for (int cc = 0; cc < 32; ++cc) {
            int c = q + cc * 4;
            a += pooled[c] * mW1[(size_t)c * 32 + j];
        }
        a += __shfl_down(a, 2, 4);
        a += __shfl_down(a, 1, 4);
        if (q == 0) y1[j] = fmaxf(a + mb1[j], 0.f);
    }
    __syncthreads();

    {
        float o = mb2[tid];
        #pragma unroll
        for (int j = 0; j < 32; ++j) o += y1[j] * mW2[j * 128 + tid];
        out[(size_t)sid * 128 + tid] = o;
    }
}

// ===========================================================================
extern "C" void kernel_launch(void* const* d_in, const int* in_sizes, int n_in,
                              void* d_out, int out_size, void* d_ws, size_t ws_size,
                              hipStream_t stream)
{
    (void)in_sizes; (void)n_in; (void)out_size; (void)ws_size;
    const float* x   = (const float*)d_in[0];
    const float* W0  = (const float*)d_in[1];
    const float* as0 = (const float*)d_in[2];
    const float* ad0 = (const float*)d_in[3];
    const float* b0  = (const float*)d_in[4];
    const float* g0  = (const float*)d_in[5];
    const float* be0 = (const float*)d_in[6];
    const float* W1  = (const float*)d_in[7];
    const float* as1 = (const float*)d_in[8];
    const float* ad1 = (const float*)d_in[9];
    const float* b1  = (const float*)d_in[10];
    const float* g1  = (const float*)d_in[11];
    const float* be1 = (const float*)d_in[12];
    const float* p   = (const float*)d_in[13];
    const float* mW1 = (const float*)d_in[14];
    const float* mb1 = (const float*)d_in[15];
    const float* mW2 = (const float*)d_in[16];
    const float* mb2 = (const float*)d_in[17];
    float* out = (float*)d_out;

    // ws layout (~151 MB; ws >= 156 MB proven by round-2 pass in RECOMP mode)
    const size_t R1B  = (size_t)N_NODES * DD * 4;     // 134,217,728
    const size_t PA0B = 4096ull * HD * 2 * 4;         //  12,582,912
    const size_t PA1B = 4096ull * DD * 2 * 4;         //   4,194,304

    char* ws = (char*)d_ws;
    float* r1  = (float*)ws;
    float* pA0 = (float*)(ws + R1B);
    float* pA1 = (float*)(ws + R1B + PA0B);
    float* vec = (float*)(ws + R1B + PA0B + PA1B);
    float* sc0 = vec;            // 512 floats (384 used)
    float* sh0 = vec + 512;
    float* sc1 = vec + 1024;
    float* sh1 = vec + 1536;
    float* pn  = vec + 2048;

    const float invN = 1.0f / (float)N_NODES;

    gat0_stats<<<N_NODES / 64, 256, 0, stream>>>(x, W0, as0, ad0, b0, pA0);
    bn_reduce<<<HD, 256, 0, stream>>>(pA0, N_NODES / 64, HD, invN, g0, be0, sc0, sh0);
    compute_pn<<<1, 128, 0, stream>>>(p, pn);
    gat1_recomp<<<N_NODES / 64, 256, 0, stream>>>(x, W0, as0, ad0, b0, sc0, sh0,
                                                  W1, as1, ad1, b1, r1, pA1);
    bn_reduce<<<DD, 256, 0, stream>>>(pA1, N_NODES / 64, DD, invN, g1, be1, sc1, sh1);
    pool_mlp<<<SSTMT, 128, 0, stream>>>(r1, sc1, sh1, pn, mW1, mb1, mW2, mb2, out);
}

// Round 4
// 1199.245 us; speedup vs baseline: 1.8580x; 1.5300x over previous
//
#include <hip/hip_runtime.h>
#include <math.h>

// Problem constants (fixed by reference setup_inputs)
#define N_NODES 262144      // S*T
#define SSTMT   16384
#define TT      16
#define DD      128
#define HH      3
#define HD      384         // H*D
#define EPSV    1e-5f

// ---------------------------------------------------------------------------
// stage a [64][128] fp32 tile row-major from global (row stride = 128 floats)
// ---------------------------------------------------------------------------
__device__ __forceinline__ void stage64x128(float (*dst)[128], const float* __restrict__ src)
{
    const int tid = threadIdx.x;
    #pragma unroll
    for (int j = 0; j < 8; ++j) {
        int gi = j * 256 + tid;          // 0..2047
        int row = gi >> 5;               // 0..63
        int col = (gi & 31) * 4;
        *reinterpret_cast<float4*>(&dst[row][col]) =
            *reinterpret_cast<const float4*>(&src[(size_t)row * DD + col]);
    }
}

// ---------------------------------------------------------------------------
// GEMM: acc[i][j] += A[rg*8+i][k] * B[k][c4+j], k in [0,128)
// A: LDS row-major (reads are 2-address broadcasts per wave: cheap)
// B: GLOBAL (L1/L2-resident weights), coalesced 512B per half-wave
// ---------------------------------------------------------------------------
__device__ __forceinline__ void gemm_gb(const float (*A)[128], const float* __restrict__ Bg,
                                        int bStrideF, int rg, int c4, float acc[8][4])
{
    const float* bp = Bg + c4;
    #pragma unroll 2
    for (int k = 0; k < 128; k += 4) {
        float4 b0 = *reinterpret_cast<const float4*>(bp);
        float4 b1 = *reinterpret_cast<const float4*>(bp + bStrideF);
        float4 b2 = *reinterpret_cast<const float4*>(bp + 2 * bStrideF);
        float4 b3 = *reinterpret_cast<const float4*>(bp + 3 * bStrideF);
        bp += 4 * (size_t)bStrideF;
        #pragma unroll
        for (int i = 0; i < 8; ++i) {
            float4 av = *reinterpret_cast<const float4*>(&A[rg * 8 + i][k]);
            acc[i][0] += av.x * b0.x; acc[i][1] += av.x * b0.y;
            acc[i][2] += av.x * b0.z; acc[i][3] += av.x * b0.w;
            acc[i][0] += av.y * b1.x; acc[i][1] += av.y * b1.y;
            acc[i][2] += av.y * b1.z; acc[i][3] += av.y * b1.w;
            acc[i][0] += av.z * b2.x; acc[i][1] += av.z * b2.y;
            acc[i][2] += av.z * b2.z; acc[i][3] += av.z * b2.w;
            acc[i][0] += av.w * b3.x; acc[i][1] += av.w * b3.y;
            acc[i][2] += av.w * b3.z; acc[i][3] += av.w * b3.w;
        }
    }
}

// ---------------------------------------------------------------------------
// attention logits + 2-edge segment softmax for a 64-row statement-aligned tile
// ---------------------------------------------------------------------------
__device__ __forceinline__ void attn64(const float (*hsv)[128],
                                       const float* avs, const float* avd,
                                       float* als, float* ald, float* aSw, float* aNw)
{
    const int tid = threadIdx.x;
    if (tid < 128) {
        int r = tid & 63;
        const float* av = (tid < 64) ? avs : avd;
        float s = 0.f;
        #pragma unroll 8
        for (int cc = 0; cc < 128; ++cc) {
            int c = (cc + r) & 127;       // rotate: <=2-way bank alias (free)
            s += hsv[r][c] * av[c];
        }
        if (tid < 64) als[r] = s; else ald[r] = s;
    }
    __syncthreads();
    if (tid < 64) {
        int r = tid;
        float es = als[r] + ald[r];
        es = es > 0.f ? es : 0.2f * es;
        float aSv = 1.f, aNv = 0.f;
        if ((r & 15) != 15) {
            float en = als[r + 1] + ald[r];
            en = en > 0.f ? en : 0.2f * en;
            float m = fmaxf(es, en);
            float xse = expf(es - m), xne = expf(en - m);
            float den = xse + xne;
            aSv = xse / den; aNv = xne / den;
        }
        aSw[r] = aSv; aNw[r] = aNv;
    }
    __syncthreads();
}

// ---------------------------------------------------------------------------
// Pass 1: layer-0 forward for BN0 statistics only.
// Grid 4096 x 256 thr; 64 statement-aligned rows/block; LDS ~70KB -> 2 blk/CU.
// ---------------------------------------------------------------------------
__global__ __launch_bounds__(256, 2)
void gat0_stats(const float* __restrict__ x, const float* __restrict__ W0,
                const float* __restrict__ as0, const float* __restrict__ ad0,
                const float* __restrict__ b0, float* __restrict__ pA0)
{
    __shared__ float xs[64][128];
    __shared__ float hs[64][128];
    __shared__ float avs[128], avd[128];
    __shared__ float als[64], ald[64], aSw[64], aNw[64];
    __shared__ float bns[8][128];

    const int tid = threadIdx.x;
    const int bid = blockIdx.x;
    const int rg = tid >> 5;          // 0..7 -> rows rg*8..rg*8+7
    const int c4 = (tid & 31) * 4;
    const size_t rb = (size_t)bid * 64;

    stage64x128(xs, x + rb * DD);
    __syncthreads();

    float psum[HH][4], qsum[HH][4];
    #pragma unroll
    for (int h = 0; h < HH; ++h)
        #pragma unroll
        for (int j = 0; j < 4; ++j) { psum[h][j] = 0.f; qsum[h][j] = 0.f; }

    for (int h = 0; h < HH; ++h) {
        float acc[8][4];
        #pragma unroll
        for (int i = 0; i < 8; ++i)
            #pragma unroll
            for (int j = 0; j < 4; ++j) acc[i][j] = 0.f;

        gemm_gb(xs, W0 + h * DD, HD, rg, c4, acc);

        __syncthreads();                   // prior hs readers done
        #pragma unroll
        for (int i = 0; i < 8; ++i) {
            float4 v; v.x = acc[i][0]; v.y = acc[i][1]; v.z = acc[i][2]; v.w = acc[i][3];
            *reinterpret_cast<float4*>(&hs[rg * 8 + i][c4]) = v;
        }
        if (tid < 128) { avs[tid] = as0[h * DD + tid]; avd[tid] = ad0[h * DD + tid]; }
        __syncthreads();
        attn64(hs, avs, avd, als, ald, aSw, aNw);

        float4 bb = *reinterpret_cast<const float4*>(&b0[h * DD + c4]);
        #pragma unroll
        for (int i = 0; i < 8; ++i) {
            int r = rg * 8 + i;
            float4 hv = *reinterpret_cast<const float4*>(&hs[r][c4]);
            float4 hx = hv;
            if ((r & 15) != 15) hx = *reinterpret_cast<const float4*>(&hs[r + 1][c4]);
            float a_s = aSw[r], a_n = aNw[r];
            float o0 = fmaxf(a_s * hv.x + a_n * hx.x + bb.x, 0.f);
            float o1 = fmaxf(a_s * hv.y + a_n * hx.y + bb.y, 0.f);
            float o2 = fmaxf(a_s * hv.z + a_n * hx.z + bb.z, 0.f);
            float o3 = fmaxf(a_s * hv.w + a_n * hx.w + bb.w, 0.f);
            psum[h][0] += o0; qsum[h][0] += o0 * o0;
            psum[h][1] += o1; qsum[h][1] += o1 * o1;
            psum[h][2] += o2; qsum[h][2] += o2 * o2;
            psum[h][3] += o3; qsum[h][3] += o3 * o3;
        }
    }

    // flush BN0 partials per head
    for (int h = 0; h < HH; ++h) {
        __syncthreads();
        #pragma unroll
        for (int j = 0; j < 4; ++j) {
            float s = psum[h][j] + __shfl_down(psum[h][j], 32);
            float q = qsum[h][j] + __shfl_down(qsum[h][j], 32);
            if ((tid & 63) < 32) {
                int w = tid >> 6;
                bns[w][c4 + j] = s;
                bns[4 + w][c4 + j] = q;
            }
        }
        __syncthreads();
        if (tid < 128) {
            float s = bns[0][tid] + bns[1][tid] + bns[2][tid] + bns[3][tid];
            float q = bns[4][tid] + bns[5][tid] + bns[6][tid] + bns[7][tid];
            size_t idx = ((size_t)bid * HD + h * DD + tid) * 2;
            pA0[idx] = s; pA0[idx + 1] = q;
        }
    }
}

// ---------------------------------------------------------------------------
// Pass 3: recompute layer-0 (BN0 applied), interleaved layer-1 GEMM per head,
// layer-1 attention, write r1 + BN1 partials.
// ---------------------------------------------------------------------------
__global__ __launch_bounds__(256, 2)
void gat1_recomp(const float* __restrict__ x, const float* __restrict__ W0,
                 const float* __restrict__ as0, const float* __restrict__ ad0,
                 const float* __restrict__ b0, const float* __restrict__ sc0,
                 const float* __restrict__ sh0, const float* __restrict__ W1,
                 const float* __restrict__ as1, const float* __restrict__ ad1,
                 const float* __restrict__ b1,
                 float* __restrict__ r1, float* __restrict__ pA1)
{
    __shared__ float xs[64][128];
    __shared__ float hs[64][128];
    __shared__ float avs[128], avd[128];
    __shared__ float als[64], ald[64], aSw[64], aNw[64];
    __shared__ float bns[8][128];

    const int tid = threadIdx.x;
    const int bid = blockIdx.x;
    const int rg = tid >> 5;
    const int c4 = (tid & 31) * 4;
    const size_t rb = (size_t)bid * 64;

    stage64x128(xs, x + rb * DD);
    __syncthreads();

    float acc2[8][4];                      // layer-1 accumulator (K=384)
    #pragma unroll
    for (int i = 0; i < 8; ++i)
        #pragma unroll
        for (int j = 0; j < 4; ++j) acc2[i][j] = 0.f;

    for (int h = 0; h < HH; ++h) {
        // ---- layer-0 GEMM for head h (B from global) ----
        float acc[8][4];
        #pragma unroll
        for (int i = 0; i < 8; ++i)
            #pragma unroll
            for (int j = 0; j < 4; ++j) acc[i][j] = 0.f;

        gemm_gb(xs, W0 + h * DD, HD, rg, c4, acc);

        __syncthreads();                   // prev head's GEMM1 reads of hs done
        #pragma unroll
        for (int i = 0; i < 8; ++i) {
            float4 v; v.x = acc[i][0]; v.y = acc[i][1]; v.z = acc[i][2]; v.w = acc[i][3];
            *reinterpret_cast<float4*>(&hs[rg * 8 + i][c4]) = v;
        }
        if (tid < 128) { avs[tid] = as0[h * DD + tid]; avd[tid] = ad0[h * DD + tid]; }
        __syncthreads();
        attn64(hs, avs, avd, als, ald, aSw, aNw);

        // ---- aggregate + b0 + relu + BN0 -> regs ----
        float4 bb  = *reinterpret_cast<const float4*>(&b0[h * DD + c4]);
        float4 scv = *reinterpret_cast<const float4*>(&sc0[h * DD + c4]);
        float4 shv = *reinterpret_cast<const float4*>(&sh0[h * DD + c4]);
        float rr[8][4];
        #pragma unroll
        for (int i = 0; i < 8; ++i) {
            int r = rg * 8 + i;
            float4 hv = *reinterpret_cast<const float4*>(&hs[r][c4]);
            float4 hx = hv;
            if ((r & 15) != 15) hx = *reinterpret_cast<const float4*>(&hs[r + 1][c4]);
            float a_s = aSw[r], a_n = aNw[r];
            rr[i][0] = fmaxf(a_s * hv.x + a_n * hx.x + bb.x, 0.f) * scv.x + shv.x;
            rr[i][1] = fmaxf(a_s * hv.y + a_n * hx.y + bb.y, 0.f) * scv.y + shv.y;
            rr[i][2] = fmaxf(a_s * hv.z + a_n * hx.z + bb.z, 0.f) * scv.z + shv.z;
            rr[i][3] = fmaxf(a_s * hv.w + a_n * hx.w + bb.w, 0.f) * scv.w + shv.w;
        }
        __syncthreads();                   // all reads of hs done
        #pragma unroll
        for (int i = 0; i < 8; ++i) {
            float4 v; v.x = rr[i][0]; v.y = rr[i][1]; v.z = rr[i][2]; v.w = rr[i][3];
            *reinterpret_cast<float4*>(&hs[rg * 8 + i][c4]) = v;
        }
        __syncthreads();

        // ---- layer-1 partial GEMM over k chunk [h*128, h*128+128) ----
        gemm_gb(hs, W1 + (size_t)(h * DD) * DD, DD, rg, c4, acc2);
    }

    // ---- layer-1 attention ----
    __syncthreads();                       // GEMM1 reads of hs done
    #pragma unroll
    for (int i = 0; i < 8; ++i) {
        float4 v; v.x = acc2[i][0]; v.y = acc2[i][1]; v.z = acc2[i][2]; v.w = acc2[i][3];
        *reinterpret_cast<float4*>(&hs[rg * 8 + i][c4]) = v;
    }
    if (tid < 128) { avs[tid] = as1[tid]; avd[tid] = ad1[tid]; }
    __syncthreads();
    attn64(hs, avs, avd, als, ald, aSw, aNw);

    // aggregate + b1 + relu -> r1 + BN1 partials
    float ps1[4] = {0, 0, 0, 0}, pq1[4] = {0, 0, 0, 0};
    float4 bb1 = *reinterpret_cast<const float4*>(&b1[c4]);
    #pragma unroll
    for (int i = 0; i < 8; ++i) {
        int r = rg * 8 + i;
        float4 hv = *reinterpret_cast<const float4*>(&hs[r][c4]);
        float4 hx = hv;
        if ((r & 15) != 15) hx = *reinterpret_cast<const float4*>(&hs[r + 1][c4]);
        float a_s = aSw[r], a_n = aNw[r];
        float o0 = fmaxf(a_s * hv.x + a_n * hx.x + bb1.x, 0.f);
        float o1 = fmaxf(a_s * hv.y + a_n * hx.y + bb1.y, 0.f);
        float o2 = fmaxf(a_s * hv.z + a_n * hx.z + bb1.z, 0.f);
        float o3 = fmaxf(a_s * hv.w + a_n * hx.w + bb1.w, 0.f);
        float4 ov; ov.x = o0; ov.y = o1; ov.z = o2; ov.w = o3;
        *reinterpret_cast<float4*>(&r1[(rb + r) * DD + c4]) = ov;
        ps1[0] += o0; pq1[0] += o0 * o0;
        ps1[1] += o1; pq1[1] += o1 * o1;
        ps1[2] += o2; pq1[2] += o2 * o2;
        ps1[3] += o3; pq1[3] += o3 * o3;
    }

    __syncthreads();
    #pragma unroll
    for (int j = 0; j < 4; ++j) {
        float s = ps1[j] + __shfl_down(ps1[j], 32);
        float q = pq1[j] + __shfl_down(pq1[j], 32);
        if ((tid & 63) < 32) {
            int w = tid >> 6;
            bns[w][c4 + j] = s;
            bns[4 + w][c4 + j] = q;
        }
    }
    __syncthreads();
    if (tid < 128) {
        float s = bns[0][tid] + bns[1][tid] + bns[2][tid] + bns[3][tid];
        float q = bns[4][tid] + bns[5][tid] + bns[6][tid] + bns[7][tid];
        size_t idx = ((size_t)bid * DD + tid) * 2;
        pA1[idx] = s; pA1[idx + 1] = q;
    }
}

// ---------------------------------------------------------------------------
// BN stat reduction: per column, sum partials -> scale/shift
// ---------------------------------------------------------------------------
__global__ __launch_bounds__(256)
void bn_reduce(const float* __restrict__ pA, int nblk, int ncol, float invN,
               const float* __restrict__ g, const float* __restrict__ be,
               float* __restrict__ sc, float* __restrict__ sh)
{
    __shared__ float rs[256], rq[256];
    int col = blockIdx.x, tid = threadIdx.x;
    float s = 0.f, q = 0.f;
    for (int i = tid; i < nblk; i += 256) {
        size_t idx = ((size_t)i * ncol + col) * 2;
        s += pA[idx]; q += pA[idx + 1];
    }
    rs[tid] = s; rq[tid] = q;
    __syncthreads();
    for (int o = 128; o > 0; o >>= 1) {
        if (tid < o) { rs[tid] += rs[tid + o]; rq[tid] += rq[tid + o]; }
        __syncthreads();
    }
    if (tid == 0) {
        float mu  = rs[0] * invN;
        float var = fmaxf(rq[0] * invN - mu * mu, 0.f);
        float inv = 1.0f / sqrtf(var + EPSV);
        float scv = g[col] * inv;
        sc[col] = scv;
        sh[col] = be[col] - mu * scv;
    }
}

__global__ __launch_bounds__(128)
void compute_pn(const float* __restrict__ p, float* __restrict__ pn)
{
    __shared__ float rs[128];
    int t = threadIdx.x;
    float v = p[t];
    rs[t] = v * v;
    __syncthreads();
    for (int o = 64; o > 0; o >>= 1) {
        if (t < o) rs[t] += rs[t + o];
        __syncthreads();
    }
    float nrm = sqrtf(rs[0]) + 1e-16f;
    pn[t] = v / nrm;
}

// ---------------------------------------------------------------------------
// Pass 5: per-statement BN1 affine + score + top-8 + tanh-weighted relu mean
// + MLP 128->32->128
// ---------------------------------------------------------------------------
__global__ __launch_bounds__(128)
void pool_mlp(const float* __restrict__ r1, const float* __restrict__ sc1,
              const float* __restrict__ sh1, const float* __restrict__ pn,
              const float* __restrict__ mW1, const float* __restrict__ mb1,
              const float* __restrict__ mW2, const float* __restrict__ mb2,
              float* __restrict__ out)
{
    __shared__ float hf[16][136];
    __shared__ float sv[16];
    __shared__ float tv[16];
    __shared__ float pooled[128];
    __shared__ float y1[32];
    int tid = threadIdx.x;
    int sid = blockIdx.x;
    float scv = sc1[tid], shv = sh1[tid];
    const float* base = r1 + (size_t)sid * TT * DD;
    #pragma unroll
    for (int i = 0; i < 16; ++i)
        hf[i][tid] = base[i * DD + tid] * scv + shv;
    __syncthreads();

    {
        int r = tid >> 3, q = tid & 7;
        float s = 0.f;
        #pragma unroll
        for (int cc = 0; cc < 16; ++cc) {
            int c = q + cc * 8;
            s += hf[r][c] * pn[c];
        }
        s += __shfl_down(s, 4, 8);
        s += __shfl_down(s, 2, 8);
        s += __shfl_down(s, 1, 8);
        if (q == 0) sv[r] = s;
    }
    __syncthreads();

    if (tid < 16) {
        float si = sv[tid];
        int rank = 0;
        #pragma unroll
        for (int u = 0; u < 16; ++u) {
            float su = sv[u];
            rank += (su > si || (su == si && u < tid)) ? 1 : 0;
        }
        tv[tid] = (rank < 8) ? tanhf(si) : 0.f;
    }
    __syncthreads();

    {
        float a = 0.f;
        #pragma unroll
        for (int rr = 0; rr < 16; ++rr)
            a += fmaxf(hf[rr][tid] * tv[rr], 0.f);
        pooled[tid] = a * 0.125f;
    }
    __syncthreads();

    {
        int j = tid >> 2, q = tid & 3;
        float a = 0.f;
        #pragma unroll
        for (int cc = 0; cc < 32; ++cc) {
            int c = q + cc * 4;
            a += pooled[c] * mW1[(size_t)c * 32 + j];
        }
        a += __shfl_down(a, 2, 4);
        a += __shfl_down(a, 1, 4);
        if (q == 0) y1[j] = fmaxf(a + mb1[j], 0.f);
    }
    __syncthreads();

    {
        float o = mb2[tid];
        #pragma unroll
        for (int j = 0; j < 32; ++j) o += y1[j] * mW2[j * 128 + tid];
        out[(size_t)sid * 128 + tid] = o;
    }
}

// ===========================================================================
extern "C" void kernel_launch(void* const* d_in, const int* in_sizes, int n_in,
                              void* d_out, int out_size, void* d_ws, size_t ws_size,
                              hipStream_t stream)
{
    (void)in_sizes; (void)n_in; (void)out_size; (void)ws_size;
    const float* x   = (const float*)d_in[0];
    const float* W0  = (const float*)d_in[1];
    const float* as0 = (const float*)d_in[2];
    const float* ad0 = (const float*)d_in[3];
    const float* b0  = (const float*)d_in[4];
    const float* g0  = (const float*)d_in[5];
    const float* be0 = (const float*)d_in[6];
    const float* W1  = (const float*)d_in[7];
    const float* as1 = (const float*)d_in[8];
    const float* ad1 = (const float*)d_in[9];
    const float* b1  = (const float*)d_in[10];
    const float* g1  = (const float*)d_in[11];
    const float* be1 = (const float*)d_in[12];
    const float* p   = (const float*)d_in[13];
    const float* mW1 = (const float*)d_in[14];
    const float* mb1 = (const float*)d_in[15];
    const float* mW2 = (const float*)d_in[16];
    const float* mb2 = (const float*)d_in[17];
    float* out = (float*)d_out;

    // ws layout (~151 MB; ws >= 156 MB proven by round-2 RECOMP pass)
    const size_t R1B  = (size_t)N_NODES * DD * 4;     // 134,217,728
    const size_t PA0B = 4096ull * HD * 2 * 4;         //  12,582,912
    const size_t PA1B = 4096ull * DD * 2 * 4;         //   4,194,304

    char* ws = (char*)d_ws;
    float* r1  = (float*)ws;
    float* pA0 = (float*)(ws + R1B);
    float* pA1 = (float*)(ws + R1B + PA0B);
    float* vec = (float*)(ws + R1B + PA0B + PA1B);
    float* sc0 = vec;            // 512 floats each slot
    float* sh0 = vec + 512;
    float* sc1 = vec + 1024;
    float* sh1 = vec + 1536;
    float* pn  = vec + 2048;

    const float invN = 1.0f / (float)N_NODES;

    gat0_stats<<<N_NODES / 64, 256, 0, stream>>>(x, W0, as0, ad0, b0, pA0);
    bn_reduce<<<HD, 256, 0, stream>>>(pA0, N_NODES / 64, HD, invN, g0, be0, sc0, sh0);
    compute_pn<<<1, 128, 0, stream>>>(p, pn);
    gat1_recomp<<<N_NODES / 64, 256, 0, stream>>>(x, W0, as0, ad0, b0, sc0, sh0,
                                                  W1, as1, ad1, b1, r1, pA1);
    bn_reduce<<<DD, 256, 0, stream>>>(pA1, N_NODES / 64, DD, invN, g1, be1, sc1, sh1);
    pool_mlp<<<SSTMT, 128, 0, stream>>>(r1, sc1, sh1, pn, mW1, mb1, mW2, mb2, out);
}